// Round 6
// baseline (3120.913 us; speedup 1.0000x reference)
//
#include <hip/hip_runtime.h>
#include <stdint.h>

#define HIDDEN 256
#define NMOLS 5000
#define APM 30
#define NATOMS 150000
#define NBONDS 320000
#define MAXNB 6
#define AFD 133
#define BFD 147
#define A1 (NATOMS + 1)
#define B1 (NBONDS + 1)
#define KI 160    // MFMA K extent for W_i GEMM (147 -> 160)
#define KO 416    // padded readout K (133 f_atoms + 27 pad + 256 amsg)

typedef __bf16 bfx8 __attribute__((ext_vector_type(8)));
typedef float fx4 __attribute__((ext_vector_type(4)));
typedef unsigned short u16x8 __attribute__((ext_vector_type(8)));

__device__ __forceinline__ float b2f(unsigned short u) {
    union { unsigned int i; float f; } v; v.i = ((unsigned int)u) << 16; return v.f;
}
__device__ __forceinline__ unsigned short f2b(float f) {
    union { float f; unsigned int i; } v; v.f = f;
    unsigned int r = v.i + 0x7FFFu + ((v.i >> 16) & 1u);
    return (unsigned short)(r >> 16);
}
__device__ __forceinline__ void gload_lds16(const void* g, void* l) {
    __builtin_amdgcn_global_load_lds(
        (const __attribute__((address_space(1))) unsigned int*)g,
        (__attribute__((address_space(3))) unsigned int*)l, 16, 0, 0);
}

// ---------------- weight conversion / padding ----------------
__global__ void k_convw(const float* __restrict__ Wi, const float* __restrict__ Wh,
                        const float* __restrict__ Wo,
                        unsigned short* __restrict__ wi, unsigned short* __restrict__ wh,
                        unsigned short* __restrict__ wo) {
    int t = blockIdx.x * 256 + threadIdx.x;
    if (t < 256 * KI) {
        int n = t / KI, k = t % KI;
        wi[t] = (k < BFD) ? f2b(Wi[n * BFD + k]) : (unsigned short)0;
        return;
    }
    int t2 = t - 256 * KI;
    if (t2 < 256 * 256) {
        wh[t2] = f2b(Wh[t2]);
        return;
    }
    int t3 = t2 - 256 * 256;
    if (t3 < 256 * KO) {
        int n = t3 / KO, k = t3 % KO;
        float v = 0.f;
        if (k < AFD) v = Wo[n * (AFD + HIDDEN) + k];
        else if (k >= 160) v = Wo[n * (AFD + HIDDEN) + AFD + (k - 160)];
        wo[t3] = f2b(v);
    }
}

// ---------------- K0: f_bonds f32 [B1][147] -> bf16 [B1][256] zero-padded ----------------
__global__ __launch_bounds__(256) void k_convfb(const float* __restrict__ fb,
                                                unsigned short* __restrict__ fbb) {
    const int gt = blockIdx.x * 256 + threadIdx.x;
    const int row = gt >> 5;
    const int s = gt & 31;
    if (row >= B1) return;
    const float* src = fb + (size_t)row * BFD;
    u16x8 o;
#pragma unroll
    for (int e = 0; e < 8; ++e) {
        const int c = s * 8 + e;
        o[e] = (c < BFD) ? f2b(src[c]) : (unsigned short)0;
    }
    *(u16x8*)(fbb + (size_t)row * HIDDEN + s * 8) = o;
}

// ---------------- K1: inp = fbb @ wi^T (gload_lds staging) ----------------
__global__ __launch_bounds__(256) void k_gemm_wi(
    const unsigned short* __restrict__ fbb, const unsigned short* __restrict__ wi,
    unsigned short* __restrict__ inp)
{
    __shared__ unsigned short lds[64 * 256];  // 32 KiB
    const int m0 = blockIdx.x * 64;
    const int tid = threadIdx.x;
    const int wv = tid >> 6, ln = tid & 63;

    {
        const int l2 = ln >> 5;
        const int q = (ln & 31) * 16;
#pragma unroll
        for (int r = 0; r < 8; ++r) {
            const int row = wv * 16 + r * 2 + l2;
            const size_t srcb = (size_t)(m0 + row) * 512 + (size_t)(q ^ ((row & 7) << 4));
            char* dst = (char*)lds + wv * 8192 + r * 1024;
            gload_lds16((const char*)fbb + srcb, dst);
        }
    }
    __syncthreads();

    const int l15 = ln & 15, lhi = ln >> 4;
    fx4 acc[4][4];
#pragma unroll
    for (int a = 0; a < 4; ++a)
#pragma unroll
        for (int b = 0; b < 4; ++b)
#pragma unroll
            for (int q = 0; q < 4; ++q) acc[a][b][q] = 0.f;

#pragma unroll
    for (int ks = 0; ks < 5; ++ks) {
        const int kk = ks * 32 + lhi * 8;
        bfx8 af[4], bb[4];
#pragma unroll
        for (int mf = 0; mf < 4; ++mf) {
            const int rr = mf * 16 + l15;
            af[mf] = *(const bfx8*)((const char*)lds + rr * 512 + ((kk * 2) ^ ((rr & 7) << 4)));
        }
#pragma unroll
        for (int nf = 0; nf < 4; ++nf) {
            const int n = wv * 64 + nf * 16 + l15;
            bb[nf] = *(const bfx8*)(wi + n * KI + kk);
        }
#pragma unroll
        for (int mf = 0; mf < 4; ++mf)
#pragma unroll
            for (int nf = 0; nf < 4; ++nf)
                acc[mf][nf] = __builtin_amdgcn_mfma_f32_16x16x32_bf16(af[mf], bb[nf], acc[mf][nf], 0, 0, 0);
    }

    __syncthreads();
    {
        const int cb = wv * 64 + l15;
        const int rb = lhi * 4;
#pragma unroll
        for (int mf = 0; mf < 4; ++mf)
#pragma unroll
            for (int j = 0; j < 4; ++j) {
                const int row = mf * 16 + rb + j;
#pragma unroll
                for (int nf = 0; nf < 4; ++nf) {
                    const int col = cb + nf * 16;
                    const int byte = (row * 512) + (((col * 2) & ~15) ^ ((row & 7) << 4)) + ((col * 2) & 15);
                    *(unsigned short*)((char*)lds + byte) = f2b(acc[mf][nf][j]);
                }
            }
    }
    __syncthreads();
#pragma unroll
    for (int i = 0; i < 8; ++i) {
        const int row = i * 8 + (tid >> 5);
        const int col16 = tid & 31;
        const int byte = row * 512 + ((col16 * 16) ^ ((row & 7) << 4));
        u16x8 c = *(const u16x8*)((const char*)lds + byte);
        const int g = m0 + row;
        if (g < B1) *(u16x8*)(inp + (size_t)g * HIDDEN + col16 * 8) = c;
    }
}

// ---------------- K_FZ: Zout = msg @ wh^T, msg computed in staging ----------------
// 32-row tile, 16 KiB LDS, target 8 blocks/CU for latency hiding.
// FIRST: msg = relu(inp);  else: msg = relu(inp + amsg[b2a] - Zprev[b2revb])
template <int FIRST>
__global__ __launch_bounds__(256, 8) void k_fz(
    const unsigned short* __restrict__ inp,
    const unsigned short* __restrict__ amsg,
    const unsigned short* __restrict__ Zprev,
    const int* __restrict__ b2a, const int* __restrict__ b2revb,
    const unsigned short* __restrict__ wh,
    unsigned short* __restrict__ Zout)
{
    __shared__ unsigned short lds[32 * 256];  // 16 KiB, XOR-swizzled A-tile
    const int m0 = blockIdx.x * 32;
    const int tid = threadIdx.x;
    const int wv = tid >> 6, ln = tid & 63;

    // reg-staging: 32 rows x 32 chunks of 16B; thread owns 4 independent row-chains
    {
        const int r0 = tid >> 5;       // 0..7
        const int c16 = tid & 31;      // 16B chunk in row
        const int co = c16 * 16;
#pragma unroll
        for (int i = 0; i < 4; ++i) {
            const int r = i * 8 + r0;
            const int b = m0 + r;
            u16x8 o;
#pragma unroll
            for (int e = 0; e < 8; ++e) o[e] = 0;
            if (b < B1) {
                u16x8 vi = *(const u16x8*)((const char*)inp + (size_t)b * 512 + co);
                if (FIRST) {
#pragma unroll
                    for (int e = 0; e < 8; ++e)
                        o[e] = (vi[e] & 0x8000u) ? (unsigned short)0 : vi[e];
                } else {
                    const int ia = b2a[b];
                    const int ir = b2revb[b];
                    u16x8 va = *(const u16x8*)((const char*)amsg + (size_t)ia * 512 + co);
                    u16x8 vz = *(const u16x8*)((const char*)Zprev + (size_t)ir * 512 + co);
#pragma unroll
                    for (int e = 0; e < 8; ++e) {
                        float v = b2f(vi[e]) + b2f(va[e]) - b2f(vz[e]);
                        o[e] = f2b(v > 0.f ? v : 0.f);
                    }
                }
            }
            *(u16x8*)((char*)lds + r * 512 + (co ^ ((r & 7) << 4))) = o;
        }
    }
    __syncthreads();

    const int l15 = ln & 15, lhi = ln >> 4;
    fx4 acc[2][4];
#pragma unroll
    for (int a = 0; a < 2; ++a)
#pragma unroll
        for (int b = 0; b < 4; ++b)
#pragma unroll
            for (int q = 0; q < 4; ++q) acc[a][b][q] = 0.f;

#pragma unroll
    for (int ks = 0; ks < 8; ++ks) {
        const int kk = ks * 32 + lhi * 8;
        bfx8 af[2], bb[4];
#pragma unroll
        for (int mf = 0; mf < 2; ++mf) {
            const int rr = mf * 16 + l15;
            af[mf] = *(const bfx8*)((const char*)lds + rr * 512 + ((kk * 2) ^ ((rr & 7) << 4)));
        }
#pragma unroll
        for (int nf = 0; nf < 4; ++nf) {
            const int n = wv * 64 + nf * 16 + l15;
            bb[nf] = *(const bfx8*)(wh + n * 256 + kk);
        }
#pragma unroll
        for (int mf = 0; mf < 2; ++mf)
#pragma unroll
            for (int nf = 0; nf < 4; ++nf)
                acc[mf][nf] = __builtin_amdgcn_mfma_f32_16x16x32_bf16(af[mf], bb[nf], acc[mf][nf], 0, 0, 0);
    }

    __syncthreads();
    {
        const int cb = wv * 64 + l15;
        const int rb = lhi * 4;
#pragma unroll
        for (int mf = 0; mf < 2; ++mf)
#pragma unroll
            for (int j = 0; j < 4; ++j) {
                const int row = mf * 16 + rb + j;
#pragma unroll
                for (int nf = 0; nf < 4; ++nf) {
                    const int col = cb + nf * 16;
                    const int byte = (row * 512) + (((col * 2) & ~15) ^ ((row & 7) << 4)) + ((col * 2) & 15);
                    *(unsigned short*)((char*)lds + byte) = f2b(acc[mf][nf][j]);
                }
            }
    }
    __syncthreads();
#pragma unroll
    for (int i = 0; i < 4; ++i) {
        const int row = i * 8 + (tid >> 5);
        const int col16 = tid & 31;
        const int byte = row * 512 + ((col16 * 16) ^ ((row & 7) << 4));
        u16x8 c = *(const u16x8*)((const char*)lds + byte);
        const int g = m0 + row;
        if (g < B1) *(u16x8*)(Zout + (size_t)g * HIDDEN + col16 * 8) = c;
    }
}

// ---------------- K_G: amsg[a] = sum_j src[a2b[a][j]] ----------------
__global__ __launch_bounds__(256) void k_gather(
    const unsigned short* __restrict__ msg, const int* __restrict__ a2b,
    unsigned short* __restrict__ amsg)
{
    const int gt = blockIdx.x * 256 + threadIdx.x;
    const int atom = gt >> 5;
    const int s = gt & 31;
    if (atom >= A1) return;
    const int* nb = a2b + atom * MAXNB;
    float acc[8];
#pragma unroll
    for (int e = 0; e < 8; ++e) acc[e] = 0.f;
#pragma unroll
    for (int j = 0; j < MAXNB; ++j) {
        const int b = nb[j];
        u16x8 v = *(const u16x8*)(msg + (size_t)b * HIDDEN + s * 8);
#pragma unroll
        for (int e = 0; e < 8; ++e) acc[e] += b2f(v[e]);
    }
    u16x8 o;
#pragma unroll
    for (int e = 0; e < 8; ++e) o[e] = f2b(acc[e]);
    *(u16x8*)(amsg + (size_t)atom * HIDDEN + s * 8) = o;
}

// ---------------- K_E: msgn[b] = relu(inp[b] + amsgZ[b2a[b]] - Z[b2revb[b]]) ----------------
__global__ __launch_bounds__(256) void k_eps(
    const unsigned short* __restrict__ inp,
    const unsigned short* __restrict__ amsgZ,
    const unsigned short* __restrict__ Z,
    const int* __restrict__ b2a, const int* __restrict__ b2revb,
    unsigned short* __restrict__ msgn)
{
    const int gt = blockIdx.x * 256 + threadIdx.x;
    const int b = gt >> 5;
    const int ss = gt & 31;
    if (b >= B1) return;
    const int ia = b2a[b];
    const int ir = b2revb[b];
    const size_t off = (size_t)b * HIDDEN + ss * 8;
    u16x8 vi = *(const u16x8*)(inp + off);
    u16x8 va = *(const u16x8*)(amsgZ + (size_t)ia * HIDDEN + ss * 8);
    u16x8 vz = *(const u16x8*)(Z + (size_t)ir * HIDDEN + ss * 8);
    u16x8 o;
#pragma unroll
    for (int e = 0; e < 8; ++e) {
        float v = b2f(vi[e]) + b2f(va[e]) - b2f(vz[e]);
        o[e] = f2b(v > 0.f ? v : 0.f);
    }
    *(u16x8*)(msgn + off) = o;
}

// ---------------- K4: atom_hiddens(bf16) = relu(concat(f_atoms, amsg) @ Wo^T + bo) ----------------
__global__ __launch_bounds__(256) void k_gemm_wo(
    const float* __restrict__ fa,
    const unsigned short* __restrict__ amsg,
    const unsigned short* __restrict__ wo,
    const float* __restrict__ bo,
    unsigned short* __restrict__ ah)
{
    __shared__ unsigned short lds[64 * KO];
    const int m0 = blockIdx.x * 64;
    const int tid = threadIdx.x;
    {
        const int r = tid >> 2, p = tid & 3;
        const int a = m0 + r;
        const bool ok = (a < A1);
        const float* src = fa + (size_t)a * AFD;
        unsigned short* drow = lds + r * KO;
#pragma unroll
        for (int i = 0; i < 13; ++i) {
            const int c0 = (i * 4 + p) * 8;
            u16x8 o;
            if (ok && c0 + 8 <= AFD) {
#pragma unroll
                for (int e = 0; e < 8; ++e) o[e] = f2b(src[c0 + e]);
            } else if (ok && c0 < AFD) {
#pragma unroll
                for (int e = 0; e < 8; ++e) o[e] = (c0 + e < AFD) ? f2b(src[c0 + e]) : (unsigned short)0;
            } else if (ok && c0 >= 160) {
                o = *(const u16x8*)(amsg + (size_t)a * HIDDEN + (c0 - 160));
            } else {
#pragma unroll
                for (int e = 0; e < 8; ++e) o[e] = 0;
            }
            *(u16x8*)(drow + c0) = o;
        }
    }
    __syncthreads();

    const int wv = tid >> 6, ln = tid & 63;
    const int l15 = ln & 15, lhi = ln >> 4;
    fx4 acc[4][4];
#pragma unroll
    for (int a = 0; a < 4; ++a)
#pragma unroll
        for (int b = 0; b < 4; ++b)
#pragma unroll
            for (int q = 0; q < 4; ++q) acc[a][b][q] = 0.f;

#pragma unroll
    for (int ks = 0; ks < 13; ++ks) {
        const int kk = ks * 32 + lhi * 8;
        bfx8 af[4], bb[4];
#pragma unroll
        for (int mf = 0; mf < 4; ++mf) {
            const int rr = mf * 16 + l15;
            af[mf] = *(const bfx8*)(lds + rr * KO + kk);
        }
#pragma unroll
        for (int nf = 0; nf < 4; ++nf) {
            const int n = wv * 64 + nf * 16 + l15;
            bb[nf] = *(const bfx8*)(wo + n * KO + kk);
        }
#pragma unroll
        for (int mf = 0; mf < 4; ++mf)
#pragma unroll
            for (int nf = 0; nf < 4; ++nf)
                acc[mf][nf] = __builtin_amdgcn_mfma_f32_16x16x32_bf16(af[mf], bb[nf], acc[mf][nf], 0, 0, 0);
    }

    __syncthreads();
    {
        const int cb = wv * 64 + l15;
        const int rb = lhi * 4;
#pragma unroll
        for (int mf = 0; mf < 4; ++mf)
#pragma unroll
            for (int j = 0; j < 4; ++j) {
                const int row = mf * 16 + rb + j;
#pragma unroll
                for (int nf = 0; nf < 4; ++nf) {
                    const int col = cb + nf * 16;
                    const int byte = (row * 512) + (((col * 2) & ~15) ^ ((row & 7) << 4)) + ((col * 2) & 15);
                    *(unsigned short*)((char*)lds + byte) = f2b(acc[mf][nf][j]);
                }
            }
    }
    __syncthreads();
#pragma unroll
    for (int i = 0; i < 8; ++i) {
        const int row = i * 8 + (tid >> 5);
        const int col16 = tid & 31;
        const int byte = row * 512 + ((col16 * 16) ^ ((row & 7) << 4));
        u16x8 c = *(const u16x8*)((const char*)lds + byte);
        const int g = m0 + row;
        if (g < A1) {
            fx4 bi0 = *(const fx4*)(bo + col16 * 8);
            fx4 bi1 = *(const fx4*)(bo + col16 * 8 + 4);
            u16x8 o;
#pragma unroll
            for (int e = 0; e < 8; ++e) {
                float v = b2f(c[e]) + (e < 4 ? bi0[e] : bi1[e - 4]);
                o[e] = f2b(v > 0.f ? v : 0.f);
            }
            *(u16x8*)(ah + (size_t)g * HIDDEN + col16 * 8) = o;
        }
    }
}

// ---------------- K5: per-molecule mean over 30 atoms ----------------
__global__ __launch_bounds__(256) void k_pool(const unsigned short* __restrict__ ah,
                                              float* __restrict__ out) {
    const int mol = blockIdx.x;
    const int h = threadIdx.x;
    const unsigned short* base = ah + ((size_t)(1 + mol * APM)) * HIDDEN + h;
    float s = 0.f;
#pragma unroll
    for (int i = 0; i < APM; ++i) s += b2f(base[(size_t)i * HIDDEN]);
    out[(size_t)mol * HIDDEN + h] = s * (1.0f / APM);
}

extern "C" void kernel_launch(void* const* d_in, const int* in_sizes, int n_in,
                              void* d_out, int out_size, void* d_ws, size_t ws_size,
                              hipStream_t stream)
{
    const float* f_atoms = (const float*)d_in[0];
    const float* f_bonds = (const float*)d_in[1];
    const int* a2b    = (const int*)d_in[2];
    const int* b2a    = (const int*)d_in[3];
    const int* b2revb = (const int*)d_in[4];
    const float* W_i  = (const float*)d_in[6];
    const float* W_h  = (const float*)d_in[7];
    const float* W_o  = (const float*)d_in[8];
    const float* b_o  = (const float*)d_in[9];
    float* out = (float*)d_out;

    char* ws = (char*)d_ws;
    size_t off = 0;
    auto alloc = [&](size_t n) { char* p = ws + off; off = (off + n + 255) & ~(size_t)255; return p; };
    unsigned short* wi   = (unsigned short*)alloc((size_t)256 * KI * 2);
    unsigned short* wh   = (unsigned short*)alloc((size_t)256 * 256 * 2);
    unsigned short* wo   = (unsigned short*)alloc((size_t)256 * KO * 2);
    unsigned short* fbb  = (unsigned short*)alloc((size_t)B1 * HIDDEN * 2 + 65536); // staged via gload_lds
    unsigned short* inp  = (unsigned short*)alloc((size_t)B1 * HIDDEN * 2);
    unsigned short* ZA   = (unsigned short*)alloc((size_t)B1 * HIDDEN * 2);
    unsigned short* amsg = (unsigned short*)alloc((size_t)A1 * HIDDEN * 2);
    unsigned short* ZB = fbb;  // fbb dead after k_gemm_wi
    unsigned short* ah = inp;  // inp dead after k_eps

    k_convw<<<832, 256, 0, stream>>>(W_i, W_h, W_o, wi, wh, wo);

    const int gb64 = (B1 + 63) / 64;            // 5001
    const int gb32 = (B1 + 31) / 32;            // 10001
    const int ga = (A1 + 63) / 64;              // 2344
    const int gg = (A1 * 32 + 255) / 256;       // 18751
    const int ge = (B1 * 32 + 255) / 256;       // 40001

    k_convfb<<<ge, 256, 0, stream>>>(f_bonds, fbb);
    k_gemm_wi<<<gb64, 256, 0, stream>>>(fbb, wi, inp);

    // t=1: Z1 = relu(inp) @ Wh^T
    k_fz<1><<<gb32, 256, 0, stream>>>(inp, nullptr, nullptr, b2a, b2revb, wh, ZA);
    k_gather<<<gg, 256, 0, stream>>>(ZA, a2b, amsg);
    // t=2..5: Zt = relu(inp + amsg[b2a] - Zprev[b2revb]) @ Wh^T   (ping-pong ZA/ZB)
    unsigned short* zc = ZA;
    unsigned short* zn = ZB;
    for (int t = 2; t <= 5; ++t) {
        k_fz<0><<<gb32, 256, 0, stream>>>(inp, amsg, zc, b2a, b2revb, wh, zn);
        k_gather<<<gg, 256, 0, stream>>>(zn, a2b, amsg);
        unsigned short* tmp = zc; zc = zn; zn = tmp;
    }
    // zc holds Z5; zn holds Z4 (dead) -> msg5
    k_eps<<<ge, 256, 0, stream>>>(inp, amsg, zc, b2a, b2revb, zn);
    k_gather<<<gg, 256, 0, stream>>>(zn, a2b, amsg);
    k_gemm_wo<<<ga, 256, 0, stream>>>(f_atoms, amsg, wo, b_o, ah);
    k_pool<<<NMOLS, 256, 0, stream>>>(ah, out);
}

// Round 7
// 1884.034 us; speedup vs baseline: 1.6565x; 1.6565x over previous
//
#include <hip/hip_runtime.h>
#include <stdint.h>

#define HIDDEN 256
#define NMOLS 5000
#define APM 30
#define NATOMS 150000
#define NBONDS 320000
#define MAXNB 6
#define AFD 133
#define BFD 147
#define A1 (NATOMS + 1)
#define B1 (NBONDS + 1)
#define KI 160    // MFMA K extent for W_i GEMM (147 -> 160)
#define KO 416    // padded readout K (133 f_atoms + 27 pad + 256 amsg)

typedef __bf16 bfx8 __attribute__((ext_vector_type(8)));
typedef float fx4 __attribute__((ext_vector_type(4)));
typedef unsigned short u16x8 __attribute__((ext_vector_type(8)));

__device__ __forceinline__ float b2f(unsigned short u) {
    union { unsigned int i; float f; } v; v.i = ((unsigned int)u) << 16; return v.f;
}
__device__ __forceinline__ unsigned short f2b(float f) {
    union { float f; unsigned int i; } v; v.f = f;
    unsigned int r = v.i + 0x7FFFu + ((v.i >> 16) & 1u);
    return (unsigned short)(r >> 16);
}
__device__ __forceinline__ void gload_lds16(const void* g, void* l) {
    __builtin_amdgcn_global_load_lds(
        (const __attribute__((address_space(1))) unsigned int*)g,
        (__attribute__((address_space(3))) unsigned int*)l, 16, 0, 0);
}

// ---------------- weight conversion / padding ----------------
__global__ void k_convw(const float* __restrict__ Wi, const float* __restrict__ Wh,
                        const float* __restrict__ Wo,
                        unsigned short* __restrict__ wi, unsigned short* __restrict__ wh,
                        unsigned short* __restrict__ wo) {
    int t = blockIdx.x * 256 + threadIdx.x;
    if (t < 256 * KI) {
        int n = t / KI, k = t % KI;
        wi[t] = (k < BFD) ? f2b(Wi[n * BFD + k]) : (unsigned short)0;
        return;
    }
    int t2 = t - 256 * KI;
    if (t2 < 256 * 256) {
        wh[t2] = f2b(Wh[t2]);
        return;
    }
    int t3 = t2 - 256 * 256;
    if (t3 < 256 * KO) {
        int n = t3 / KO, k = t3 % KO;
        float v = 0.f;
        if (k < AFD) v = Wo[n * (AFD + HIDDEN) + k];
        else if (k >= 160) v = Wo[n * (AFD + HIDDEN) + AFD + (k - 160)];
        wo[t3] = f2b(v);
    }
}

// ---------------- K0: f_bonds f32 [B1][147] -> bf16 [B1][256] zero-padded ----------------
__global__ __launch_bounds__(256) void k_convfb(const float* __restrict__ fb,
                                                unsigned short* __restrict__ fbb) {
    const int gt = blockIdx.x * 256 + threadIdx.x;
    const int row = gt >> 5;
    const int s = gt & 31;
    if (row >= B1) return;
    const float* src = fb + (size_t)row * BFD;
    u16x8 o;
#pragma unroll
    for (int e = 0; e < 8; ++e) {
        const int c = s * 8 + e;
        o[e] = (c < BFD) ? f2b(src[c]) : (unsigned short)0;
    }
    *(u16x8*)(fbb + (size_t)row * HIDDEN + s * 8) = o;
}

// ---------------- K1: inp = fbb @ wi^T (gload_lds staging) ----------------
__global__ __launch_bounds__(256) void k_gemm_wi(
    const unsigned short* __restrict__ fbb, const unsigned short* __restrict__ wi,
    unsigned short* __restrict__ inp)
{
    __shared__ unsigned short lds[64 * 256];  // 32 KiB
    const int m0 = blockIdx.x * 64;
    const int tid = threadIdx.x;
    const int wv = tid >> 6, ln = tid & 63;

    {
        const int l2 = ln >> 5;
        const int q = (ln & 31) * 16;
#pragma unroll
        for (int r = 0; r < 8; ++r) {
            const int row = wv * 16 + r * 2 + l2;
            const size_t srcb = (size_t)(m0 + row) * 512 + (size_t)(q ^ ((row & 7) << 4));
            char* dst = (char*)lds + wv * 8192 + r * 1024;
            gload_lds16((const char*)fbb + srcb, dst);
        }
    }
    __syncthreads();

    const int l15 = ln & 15, lhi = ln >> 4;
    fx4 acc[4][4];
#pragma unroll
    for (int a = 0; a < 4; ++a)
#pragma unroll
        for (int b = 0; b < 4; ++b)
#pragma unroll
            for (int q = 0; q < 4; ++q) acc[a][b][q] = 0.f;

#pragma unroll
    for (int ks = 0; ks < 5; ++ks) {
        const int kk = ks * 32 + lhi * 8;
        bfx8 af[4], bb[4];
#pragma unroll
        for (int mf = 0; mf < 4; ++mf) {
            const int rr = mf * 16 + l15;
            af[mf] = *(const bfx8*)((const char*)lds + rr * 512 + ((kk * 2) ^ ((rr & 7) << 4)));
        }
#pragma unroll
        for (int nf = 0; nf < 4; ++nf) {
            const int n = wv * 64 + nf * 16 + l15;
            bb[nf] = *(const bfx8*)(wi + n * KI + kk);
        }
#pragma unroll
        for (int mf = 0; mf < 4; ++mf)
#pragma unroll
            for (int nf = 0; nf < 4; ++nf)
                acc[mf][nf] = __builtin_amdgcn_mfma_f32_16x16x32_bf16(af[mf], bb[nf], acc[mf][nf], 0, 0, 0);
    }

    __syncthreads();
    {
        const int cb = wv * 64 + l15;
        const int rb = lhi * 4;
#pragma unroll
        for (int mf = 0; mf < 4; ++mf)
#pragma unroll
            for (int j = 0; j < 4; ++j) {
                const int row = mf * 16 + rb + j;
#pragma unroll
                for (int nf = 0; nf < 4; ++nf) {
                    const int col = cb + nf * 16;
                    const int byte = (row * 512) + (((col * 2) & ~15) ^ ((row & 7) << 4)) + ((col * 2) & 15);
                    *(unsigned short*)((char*)lds + byte) = f2b(acc[mf][nf][j]);
                }
            }
    }
    __syncthreads();
#pragma unroll
    for (int i = 0; i < 8; ++i) {
        const int row = i * 8 + (tid >> 5);
        const int col16 = tid & 31;
        const int byte = row * 512 + ((col16 * 16) ^ ((row & 7) << 4));
        u16x8 c = *(const u16x8*)((const char*)lds + byte);
        const int g = m0 + row;
        if (g < B1) *(u16x8*)(inp + (size_t)g * HIDDEN + col16 * 8) = c;
    }
}

// ---------------- K_WH: msgn = relu(inp + (amsg[b2a] - msgsrc[b2revb]) @ wh^T) ----------------
// 32-row tile, 16 KiB LDS, acc[2][4]=32 AGPR, target 5 blocks/CU without spills.
// FIRST: reverse-message source is relu(inp) read on the fly.
template <int FIRST>
__global__ __launch_bounds__(256, 5) void k_wh(
    const unsigned short* __restrict__ inp,
    const unsigned short* __restrict__ amsg,
    const unsigned short* __restrict__ msgp,
    const int* __restrict__ b2a, const int* __restrict__ b2revb,
    const unsigned short* __restrict__ wh,
    unsigned short* __restrict__ msgn)
{
    __shared__ unsigned short lds[32 * 256];  // 16 KiB, XOR-swizzled A-tile
    const int m0 = blockIdx.x * 32;
    const int tid = threadIdx.x;
    const int wv = tid >> 6, ln = tid & 63;

    // staging: A-row = amsg[b2a[b]] - (relu?)(src[b2revb[b]]); 4 independent chains/thread
    {
        const int r0 = tid >> 5;       // 0..7
        const int c16 = tid & 31;      // 16B chunk in row
        const int co = c16 * 16;
        int ia[4], ir[4];
#pragma unroll
        for (int i = 0; i < 4; ++i) {
            const int b = m0 + i * 8 + r0;
            const bool ok = (b < B1);
            ia[i] = ok ? b2a[b] : 0;
            ir[i] = ok ? b2revb[b] : 0;
        }
#pragma unroll
        for (int i = 0; i < 4; ++i) {
            const int r = i * 8 + r0;
            const int b = m0 + r;
            u16x8 o;
#pragma unroll
            for (int e = 0; e < 8; ++e) o[e] = 0;
            if (b < B1) {
                u16x8 va = *(const u16x8*)((const char*)amsg + (size_t)ia[i] * 512 + co);
                u16x8 vz;
                if (FIRST) vz = *(const u16x8*)((const char*)inp + (size_t)ir[i] * 512 + co);
                else       vz = *(const u16x8*)((const char*)msgp + (size_t)ir[i] * 512 + co);
#pragma unroll
                for (int e = 0; e < 8; ++e) {
                    float zv = b2f(vz[e]);
                    if (FIRST) zv = zv > 0.f ? zv : 0.f;
                    o[e] = f2b(b2f(va[e]) - zv);
                }
            }
            *(u16x8*)((char*)lds + r * 512 + (co ^ ((r & 7) << 4))) = o;
        }
    }
    __syncthreads();

    const int l15 = ln & 15, lhi = ln >> 4;
    fx4 acc[2][4];
#pragma unroll
    for (int a = 0; a < 2; ++a)
#pragma unroll
        for (int b = 0; b < 4; ++b)
#pragma unroll
            for (int q = 0; q < 4; ++q) acc[a][b][q] = 0.f;

#pragma unroll
    for (int ks = 0; ks < 8; ++ks) {
        const int kk = ks * 32 + lhi * 8;
        bfx8 af[2], bb[4];
#pragma unroll
        for (int mf = 0; mf < 2; ++mf) {
            const int rr = mf * 16 + l15;
            af[mf] = *(const bfx8*)((const char*)lds + rr * 512 + ((kk * 2) ^ ((rr & 7) << 4)));
        }
#pragma unroll
        for (int nf = 0; nf < 4; ++nf) {
            const int n = wv * 64 + nf * 16 + l15;
            bb[nf] = *(const bfx8*)(wh + n * 256 + kk);
        }
#pragma unroll
        for (int mf = 0; mf < 2; ++mf)
#pragma unroll
            for (int nf = 0; nf < 4; ++nf)
                acc[mf][nf] = __builtin_amdgcn_mfma_f32_16x16x32_bf16(af[mf], bb[nf], acc[mf][nf], 0, 0, 0);
    }

    // C roundtrip in the same 16 KiB LDS
    __syncthreads();
    {
        const int cb = wv * 64 + l15;
        const int rb = lhi * 4;
#pragma unroll
        for (int mf = 0; mf < 2; ++mf)
#pragma unroll
            for (int j = 0; j < 4; ++j) {
                const int row = mf * 16 + rb + j;
#pragma unroll
                for (int nf = 0; nf < 4; ++nf) {
                    const int col = cb + nf * 16;
                    const int byte = (row * 512) + (((col * 2) & ~15) ^ ((row & 7) << 4)) + ((col * 2) & 15);
                    *(unsigned short*)((char*)lds + byte) = f2b(acc[mf][nf][j]);
                }
            }
    }
    __syncthreads();
    // epilogue: msgn = relu(inp + C), fully vectorized
#pragma unroll
    for (int i = 0; i < 4; ++i) {
        const int row = i * 8 + (tid >> 5);
        const int col16 = tid & 31;
        const int byte = row * 512 + ((col16 * 16) ^ ((row & 7) << 4));
        u16x8 c = *(const u16x8*)((const char*)lds + byte);
        const int g = m0 + row;
        if (g < B1) {
            const size_t off = (size_t)g * HIDDEN + col16 * 8;
            u16x8 vi = *(const u16x8*)(inp + off);
            u16x8 o;
#pragma unroll
            for (int e = 0; e < 8; ++e) {
                float v = b2f(vi[e]) + b2f(c[e]);
                o[e] = f2b(v > 0.f ? v : 0.f);
            }
            *(u16x8*)(msgn + off) = o;
        }
    }
}

// ---------------- K_G: amsg[a] = sum_j (relu?)(src[a2b[a][j]]) ----------------
template <int RELU>
__global__ __launch_bounds__(256) void k_gather(
    const unsigned short* __restrict__ msg, const int* __restrict__ a2b,
    unsigned short* __restrict__ amsg)
{
    const int gt = blockIdx.x * 256 + threadIdx.x;
    const int atom = gt >> 5;
    const int s = gt & 31;
    if (atom >= A1) return;
    const int* nb = a2b + atom * MAXNB;
    float acc[8];
#pragma unroll
    for (int e = 0; e < 8; ++e) acc[e] = 0.f;
#pragma unroll
    for (int j = 0; j < MAXNB; ++j) {
        const int b = nb[j];
        u16x8 v = *(const u16x8*)(msg + (size_t)b * HIDDEN + s * 8);
#pragma unroll
        for (int e = 0; e < 8; ++e) {
            float x = b2f(v[e]);
            if (RELU) x = x > 0.f ? x : 0.f;
            acc[e] += x;
        }
    }
    u16x8 o;
#pragma unroll
    for (int e = 0; e < 8; ++e) o[e] = f2b(acc[e]);
    *(u16x8*)(amsg + (size_t)atom * HIDDEN + s * 8) = o;
}

// ---------------- K4: atom_hiddens(bf16) = relu(concat(f_atoms, amsg) @ Wo^T + bo) ----------------
__global__ __launch_bounds__(256) void k_gemm_wo(
    const float* __restrict__ fa,
    const unsigned short* __restrict__ amsg,
    const unsigned short* __restrict__ wo,
    const float* __restrict__ bo,
    unsigned short* __restrict__ ah)
{
    __shared__ unsigned short lds[64 * KO];
    const int m0 = blockIdx.x * 64;
    const int tid = threadIdx.x;
    {
        const int r = tid >> 2, p = tid & 3;
        const int a = m0 + r;
        const bool ok = (a < A1);
        const float* src = fa + (size_t)a * AFD;
        unsigned short* drow = lds + r * KO;
#pragma unroll
        for (int i = 0; i < 13; ++i) {
            const int c0 = (i * 4 + p) * 8;
            u16x8 o;
            if (ok && c0 + 8 <= AFD) {
#pragma unroll
                for (int e = 0; e < 8; ++e) o[e] = f2b(src[c0 + e]);
            } else if (ok && c0 < AFD) {
#pragma unroll
                for (int e = 0; e < 8; ++e) o[e] = (c0 + e < AFD) ? f2b(src[c0 + e]) : (unsigned short)0;
            } else if (ok && c0 >= 160) {
                o = *(const u16x8*)(amsg + (size_t)a * HIDDEN + (c0 - 160));
            } else {
#pragma unroll
                for (int e = 0; e < 8; ++e) o[e] = 0;
            }
            *(u16x8*)(drow + c0) = o;
        }
    }
    __syncthreads();

    const int wv = tid >> 6, ln = tid & 63;
    const int l15 = ln & 15, lhi = ln >> 4;
    fx4 acc[4][4];
#pragma unroll
    for (int a = 0; a < 4; ++a)
#pragma unroll
        for (int b = 0; b < 4; ++b)
#pragma unroll
            for (int q = 0; q < 4; ++q) acc[a][b][q] = 0.f;

#pragma unroll
    for (int ks = 0; ks < 13; ++ks) {
        const int kk = ks * 32 + lhi * 8;
        bfx8 af[4], bb[4];
#pragma unroll
        for (int mf = 0; mf < 4; ++mf) {
            const int rr = mf * 16 + l15;
            af[mf] = *(const bfx8*)(lds + rr * KO + kk);
        }
#pragma unroll
        for (int nf = 0; nf < 4; ++nf) {
            const int n = wv * 64 + nf * 16 + l15;
            bb[nf] = *(const bfx8*)(wo + n * KO + kk);
        }
#pragma unroll
        for (int mf = 0; mf < 4; ++mf)
#pragma unroll
            for (int nf = 0; nf < 4; ++nf)
                acc[mf][nf] = __builtin_amdgcn_mfma_f32_16x16x32_bf16(af[mf], bb[nf], acc[mf][nf], 0, 0, 0);
    }

    __syncthreads();
    {
        const int cb = wv * 64 + l15;
        const int rb = lhi * 4;
#pragma unroll
        for (int mf = 0; mf < 4; ++mf)
#pragma unroll
            for (int j = 0; j < 4; ++j) {
                const int row = mf * 16 + rb + j;
#pragma unroll
                for (int nf = 0; nf < 4; ++nf) {
                    const int col = cb + nf * 16;
                    const int byte = (row * 512) + (((col * 2) & ~15) ^ ((row & 7) << 4)) + ((col * 2) & 15);
                    *(unsigned short*)((char*)lds + byte) = f2b(acc[mf][nf][j]);
                }
            }
    }
    __syncthreads();
#pragma unroll
    for (int i = 0; i < 8; ++i) {
        const int row = i * 8 + (tid >> 5);
        const int col16 = tid & 31;
        const int byte = row * 512 + ((col16 * 16) ^ ((row & 7) << 4));
        u16x8 c = *(const u16x8*)((const char*)lds + byte);
        const int g = m0 + row;
        if (g < A1) {
            fx4 bi0 = *(const fx4*)(bo + col16 * 8);
            fx4 bi1 = *(const fx4*)(bo + col16 * 8 + 4);
            u16x8 o;
#pragma unroll
            for (int e = 0; e < 8; ++e) {
                float v = b2f(c[e]) + (e < 4 ? bi0[e] : bi1[e - 4]);
                o[e] = f2b(v > 0.f ? v : 0.f);
            }
            *(u16x8*)(ah + (size_t)g * HIDDEN + col16 * 8) = o;
        }
    }
}

// ---------------- K5: per-molecule mean over 30 atoms ----------------
__global__ __launch_bounds__(256) void k_pool(const unsigned short* __restrict__ ah,
                                              float* __restrict__ out) {
    const int mol = blockIdx.x;
    const int h = threadIdx.x;
    const unsigned short* base = ah + ((size_t)(1 + mol * APM)) * HIDDEN + h;
    float s = 0.f;
#pragma unroll
    for (int i = 0; i < APM; ++i) s += b2f(base[(size_t)i * HIDDEN]);
    out[(size_t)mol * HIDDEN + h] = s * (1.0f / APM);
}

extern "C" void kernel_launch(void* const* d_in, const int* in_sizes, int n_in,
                              void* d_out, int out_size, void* d_ws, size_t ws_size,
                              hipStream_t stream)
{
    const float* f_atoms = (const float*)d_in[0];
    const float* f_bonds = (const float*)d_in[1];
    const int* a2b    = (const int*)d_in[2];
    const int* b2a    = (const int*)d_in[3];
    const int* b2revb = (const int*)d_in[4];
    const float* W_i  = (const float*)d_in[6];
    const float* W_h  = (const float*)d_in[7];
    const float* W_o  = (const float*)d_in[8];
    const float* b_o  = (const float*)d_in[9];
    float* out = (float*)d_out;

    char* ws = (char*)d_ws;
    size_t off = 0;
    auto alloc = [&](size_t n) { char* p = ws + off; off = (off + n + 255) & ~(size_t)255; return p; };
    unsigned short* wi   = (unsigned short*)alloc((size_t)256 * KI * 2);
    unsigned short* wh   = (unsigned short*)alloc((size_t)256 * 256 * 2);
    unsigned short* wo   = (unsigned short*)alloc((size_t)256 * KO * 2);
    unsigned short* fbb  = (unsigned short*)alloc((size_t)B1 * HIDDEN * 2 + 65536); // gload slop
    unsigned short* inp  = (unsigned short*)alloc((size_t)B1 * HIDDEN * 2);
    unsigned short* msgA = (unsigned short*)alloc((size_t)B1 * HIDDEN * 2);
    unsigned short* amsg = (unsigned short*)alloc((size_t)A1 * HIDDEN * 2);
    unsigned short* msgB = fbb;   // fbb dead after k_gemm_wi
    unsigned short* ah   = inp;   // inp dead after last k_wh

    k_convw<<<832, 256, 0, stream>>>(W_i, W_h, W_o, wi, wh, wo);

    const int gb64 = (B1 + 63) / 64;            // 5001
    const int gb32 = (B1 + 31) / 32;            // 10001
    const int ga = (A1 + 63) / 64;              // 2344
    const int gg = (A1 * 32 + 255) / 256;       // 18751
    const int gc = (B1 * 32 + 255) / 256;       // 40001

    k_convfb<<<gc, 256, 0, stream>>>(f_bonds, fbb);
    k_gemm_wi<<<gb64, 256, 0, stream>>>(fbb, wi, inp);

    // t=1: amsg = gather(relu(inp)); msg1 = relu(inp + (amsg[b2a] - relu(inp[b2revb]))@Wh^T)
    k_gather<1><<<gg, 256, 0, stream>>>(inp, a2b, amsg);
    k_wh<1><<<gb32, 256, 0, stream>>>(inp, amsg, nullptr, b2a, b2revb, wh, msgA);

    // t=2..5 (ping-pong msgA/msgB; msgB overlays fbb which is now dead)
    unsigned short* cur = msgA;
    unsigned short* nxt = msgB;
    for (int t = 2; t <= 5; ++t) {
        k_gather<0><<<gg, 256, 0, stream>>>(cur, a2b, amsg);
        k_wh<0><<<gb32, 256, 0, stream>>>(inp, amsg, cur, b2a, b2revb, wh, nxt);
        unsigned short* tmp = cur; cur = nxt; nxt = tmp;
    }
    // cur = msg5
    k_gather<0><<<gg, 256, 0, stream>>>(cur, a2b, amsg);
    k_gemm_wo<<<ga, 256, 0, stream>>>(f_atoms, amsg, wo, b_o, ah);
    k_pool<<<NMOLS, 256, 0, stream>>>(ah, out);
}

// Round 8
// 1846.698 us; speedup vs baseline: 1.6900x; 1.0202x over previous
//
#include <hip/hip_runtime.h>
#include <stdint.h>

#define HIDDEN 256
#define NMOLS 5000
#define APM 30
#define NATOMS 150000
#define NBONDS 320000
#define MAXNB 6
#define AFD 133
#define BFD 147
#define A1 (NATOMS + 1)
#define B1 (NBONDS + 1)
#define KI 160    // MFMA K extent for W_i GEMM (147 -> 160)
#define KO 416    // padded readout K (133 f_atoms + 27 pad + 256 amsg)

typedef __bf16 bfx8 __attribute__((ext_vector_type(8)));
typedef float fx4 __attribute__((ext_vector_type(4)));
typedef unsigned short u16x8 __attribute__((ext_vector_type(8)));

__device__ __forceinline__ float b2f(unsigned short u) {
    union { unsigned int i; float f; } v; v.i = ((unsigned int)u) << 16; return v.f;
}
__device__ __forceinline__ unsigned short f2b(float f) {
    union { float f; unsigned int i; } v; v.f = f;
    unsigned int r = v.i + 0x7FFFu + ((v.i >> 16) & 1u);
    return (unsigned short)(r >> 16);
}
__device__ __forceinline__ void gload_lds16(const void* g, void* l) {
    __builtin_amdgcn_global_load_lds(
        (const __attribute__((address_space(1))) unsigned int*)g,
        (__attribute__((address_space(3))) unsigned int*)l, 16, 0, 0);
}

// ---------------- weight conversion / padding ----------------
__global__ void k_convw(const float* __restrict__ Wi, const float* __restrict__ Wh,
                        const float* __restrict__ Wo,
                        unsigned short* __restrict__ wi, unsigned short* __restrict__ wh,
                        unsigned short* __restrict__ wo) {
    int t = blockIdx.x * 256 + threadIdx.x;
    if (t < 256 * KI) {
        int n = t / KI, k = t % KI;
        wi[t] = (k < BFD) ? f2b(Wi[n * BFD + k]) : (unsigned short)0;
        return;
    }
    int t2 = t - 256 * KI;
    if (t2 < 256 * 256) {
        wh[t2] = f2b(Wh[t2]);
        return;
    }
    int t3 = t2 - 256 * 256;
    if (t3 < 256 * KO) {
        int n = t3 / KO, k = t3 % KO;
        float v = 0.f;
        if (k < AFD) v = Wo[n * (AFD + HIDDEN) + k];
        else if (k >= 160) v = Wo[n * (AFD + HIDDEN) + AFD + (k - 160)];
        wo[t3] = f2b(v);
    }
}

// ---------------- K0: f_bonds f32 [B1][147] -> bf16 [B1][256] zero-padded ----------------
__global__ __launch_bounds__(256) void k_convfb(const float* __restrict__ fb,
                                                unsigned short* __restrict__ fbb) {
    const int gt = blockIdx.x * 256 + threadIdx.x;
    const int row = gt >> 5;
    const int s = gt & 31;
    if (row >= B1) return;
    const float* src = fb + (size_t)row * BFD;
    u16x8 o;
#pragma unroll
    for (int e = 0; e < 8; ++e) {
        const int c = s * 8 + e;
        o[e] = (c < BFD) ? f2b(src[c]) : (unsigned short)0;
    }
    *(u16x8*)(fbb + (size_t)row * HIDDEN + s * 8) = o;
}

// ---------------- K1: inp = fbb @ wi^T (gload_lds staging) ----------------
__global__ __launch_bounds__(256) void k_gemm_wi(
    const unsigned short* __restrict__ fbb, const unsigned short* __restrict__ wi,
    unsigned short* __restrict__ inp)
{
    __shared__ unsigned short lds[64 * 256];  // 32 KiB
    const int m0 = blockIdx.x * 64;
    const int tid = threadIdx.x;
    const int wv = tid >> 6, ln = tid & 63;

    {
        const int l2 = ln >> 5;
        const int q = (ln & 31) * 16;
#pragma unroll
        for (int r = 0; r < 8; ++r) {
            const int row = wv * 16 + r * 2 + l2;
            const size_t srcb = (size_t)(m0 + row) * 512 + (size_t)(q ^ ((row & 7) << 4));
            char* dst = (char*)lds + wv * 8192 + r * 1024;
            gload_lds16((const char*)fbb + srcb, dst);
        }
    }
    __syncthreads();

    const int l15 = ln & 15, lhi = ln >> 4;
    fx4 acc[4][4];
#pragma unroll
    for (int a = 0; a < 4; ++a)
#pragma unroll
        for (int b = 0; b < 4; ++b)
#pragma unroll
            for (int q = 0; q < 4; ++q) acc[a][b][q] = 0.f;

#pragma unroll
    for (int ks = 0; ks < 5; ++ks) {
        const int kk = ks * 32 + lhi * 8;
        bfx8 af[4], bb[4];
#pragma unroll
        for (int mf = 0; mf < 4; ++mf) {
            const int rr = mf * 16 + l15;
            af[mf] = *(const bfx8*)((const char*)lds + rr * 512 + ((kk * 2) ^ ((rr & 7) << 4)));
        }
#pragma unroll
        for (int nf = 0; nf < 4; ++nf) {
            const int n = wv * 64 + nf * 16 + l15;
            bb[nf] = *(const bfx8*)(wi + n * KI + kk);
        }
#pragma unroll
        for (int mf = 0; mf < 4; ++mf)
#pragma unroll
            for (int nf = 0; nf < 4; ++nf)
                acc[mf][nf] = __builtin_amdgcn_mfma_f32_16x16x32_bf16(af[mf], bb[nf], acc[mf][nf], 0, 0, 0);
    }

    __syncthreads();
    {
        const int cb = wv * 64 + l15;
        const int rb = lhi * 4;
#pragma unroll
        for (int mf = 0; mf < 4; ++mf)
#pragma unroll
            for (int j = 0; j < 4; ++j) {
                const int row = mf * 16 + rb + j;
#pragma unroll
                for (int nf = 0; nf < 4; ++nf) {
                    const int col = cb + nf * 16;
                    const int byte = (row * 512) + (((col * 2) & ~15) ^ ((row & 7) << 4)) + ((col * 2) & 15);
                    *(unsigned short*)((char*)lds + byte) = f2b(acc[mf][nf][j]);
                }
            }
    }
    __syncthreads();
#pragma unroll
    for (int i = 0; i < 8; ++i) {
        const int row = i * 8 + (tid >> 5);
        const int col16 = tid & 31;
        const int byte = row * 512 + ((col16 * 16) ^ ((row & 7) << 4));
        u16x8 c = *(const u16x8*)((const char*)lds + byte);
        const int g = m0 + row;
        if (g < B1) *(u16x8*)(inp + (size_t)g * HIDDEN + col16 * 8) = c;
    }
}

// ---------------- K_Z: Z = src @ wh^T  (dense, streaming) ----------------
// FIRST=1: src rows are relu(inp) computed on the fly (register staging).
// FIRST=0: src read directly via global_load_lds (pre-swizzled source).
template <int FIRST>
__global__ __launch_bounds__(256) void k_gemm_z(
    const unsigned short* __restrict__ src,
    const unsigned short* __restrict__ wh,
    unsigned short* __restrict__ Z)
{
    __shared__ unsigned short lds[64 * 256];  // 32 KiB, XOR-swizzled A-tile
    const int m0 = blockIdx.x * 64;
    const int tid = threadIdx.x;
    const int wv = tid >> 6, ln = tid & 63;

    if (FIRST) {
        // register staging with relu-on-read (sequential)
        const int r0 = tid >> 5;       // 0..7
        const int c16 = tid & 31;
        const int co = c16 * 16;
#pragma unroll
        for (int i = 0; i < 8; ++i) {
            const int r = i * 8 + r0;
            const int b = m0 + r;
            u16x8 o;
#pragma unroll
            for (int e = 0; e < 8; ++e) o[e] = 0;
            if (b < B1) {
                u16x8 vi = *(const u16x8*)((const char*)src + (size_t)b * 512 + co);
#pragma unroll
                for (int e = 0; e < 8; ++e)
                    o[e] = (vi[e] & 0x8000u) ? (unsigned short)0 : vi[e];
            }
            *(u16x8*)((char*)lds + r * 512 + (co ^ ((r & 7) << 4))) = o;
        }
    } else {
        // async global->LDS, linear dest + pre-swizzled source
        const int l2 = ln >> 5;
        const int q = (ln & 31) * 16;
#pragma unroll
        for (int r = 0; r < 8; ++r) {
            const int row = wv * 16 + r * 2 + l2;
            const size_t srcb = (size_t)(m0 + row) * 512 + (size_t)(q ^ ((row & 7) << 4));
            char* dst = (char*)lds + wv * 8192 + r * 1024;
            gload_lds16((const char*)src + srcb, dst);
        }
    }
    __syncthreads();

    const int l15 = ln & 15, lhi = ln >> 4;
    fx4 acc[4][4];
#pragma unroll
    for (int a = 0; a < 4; ++a)
#pragma unroll
        for (int b = 0; b < 4; ++b)
#pragma unroll
            for (int q = 0; q < 4; ++q) acc[a][b][q] = 0.f;

#pragma unroll
    for (int ks = 0; ks < 8; ++ks) {
        const int kk = ks * 32 + lhi * 8;
        bfx8 af[4], bb[4];
#pragma unroll
        for (int mf = 0; mf < 4; ++mf) {
            const int rr = mf * 16 + l15;
            af[mf] = *(const bfx8*)((const char*)lds + rr * 512 + ((kk * 2) ^ ((rr & 7) << 4)));
        }
#pragma unroll
        for (int nf = 0; nf < 4; ++nf) {
            const int n = wv * 64 + nf * 16 + l15;
            bb[nf] = *(const bfx8*)(wh + n * 256 + kk);
        }
#pragma unroll
        for (int mf = 0; mf < 4; ++mf)
#pragma unroll
            for (int nf = 0; nf < 4; ++nf)
                acc[mf][nf] = __builtin_amdgcn_mfma_f32_16x16x32_bf16(af[mf], bb[nf], acc[mf][nf], 0, 0, 0);
    }

    // C roundtrip -> coalesced u16x8 stores of Z
    __syncthreads();
    {
        const int cb = wv * 64 + l15;
        const int rb = lhi * 4;
#pragma unroll
        for (int mf = 0; mf < 4; ++mf)
#pragma unroll
            for (int j = 0; j < 4; ++j) {
                const int row = mf * 16 + rb + j;
#pragma unroll
                for (int nf = 0; nf < 4; ++nf) {
                    const int col = cb + nf * 16;
                    const int byte = (row * 512) + (((col * 2) & ~15) ^ ((row & 7) << 4)) + ((col * 2) & 15);
                    *(unsigned short*)((char*)lds + byte) = f2b(acc[mf][nf][j]);
                }
            }
    }
    __syncthreads();
#pragma unroll
    for (int i = 0; i < 8; ++i) {
        const int row = i * 8 + (tid >> 5);
        const int col16 = tid & 31;
        const int byte = row * 512 + ((col16 * 16) ^ ((row & 7) << 4));
        u16x8 c = *(const u16x8*)((const char*)lds + byte);
        const int g = m0 + row;
        if (g < B1) *(u16x8*)(Z + (size_t)g * HIDDEN + col16 * 8) = c;
    }
}

// ---------------- K_G: amsg[a] = sum_j src[a2b[a][j]] ----------------
__global__ __launch_bounds__(256) void k_gather(
    const unsigned short* __restrict__ msg, const int* __restrict__ a2b,
    unsigned short* __restrict__ amsg)
{
    const int gt = blockIdx.x * 256 + threadIdx.x;
    const int atom = gt >> 5;
    const int s = gt & 31;
    if (atom >= A1) return;
    const int* nb = a2b + atom * MAXNB;
    float acc[8];
#pragma unroll
    for (int e = 0; e < 8; ++e) acc[e] = 0.f;
#pragma unroll
    for (int j = 0; j < MAXNB; ++j) {
        const int b = nb[j];
        u16x8 v = *(const u16x8*)(msg + (size_t)b * HIDDEN + s * 8);
#pragma unroll
        for (int e = 0; e < 8; ++e) acc[e] += b2f(v[e]);
    }
    u16x8 o;
#pragma unroll
    for (int e = 0; e < 8; ++e) o[e] = f2b(acc[e]);
    *(u16x8*)(amsg + (size_t)atom * HIDDEN + s * 8) = o;
}

// ---------------- K_E: msgn[b] = relu(inp[b] + amsgZ[b2a[b]] - Z[b2revb[b]]) ----------------
__global__ __launch_bounds__(256) void k_eps(
    const unsigned short* __restrict__ inp,
    const unsigned short* __restrict__ amsgZ,
    const unsigned short* __restrict__ Z,
    const int* __restrict__ b2a, const int* __restrict__ b2revb,
    unsigned short* __restrict__ msgn)
{
    const int gt = blockIdx.x * 256 + threadIdx.x;
    const int b = gt >> 5;
    const int ss = gt & 31;
    if (b >= B1) return;
    const int ia = b2a[b];
    const int ir = b2revb[b];
    const size_t off = (size_t)b * HIDDEN + ss * 8;
    u16x8 vi = *(const u16x8*)(inp + off);
    u16x8 va = *(const u16x8*)(amsgZ + (size_t)ia * HIDDEN + ss * 8);
    u16x8 vz = *(const u16x8*)(Z + (size_t)ir * HIDDEN + ss * 8);
    u16x8 o;
#pragma unroll
    for (int e = 0; e < 8; ++e) {
        float v = b2f(vi[e]) + b2f(va[e]) - b2f(vz[e]);
        o[e] = f2b(v > 0.f ? v : 0.f);
    }
    *(u16x8*)(msgn + off) = o;
}

// ---------------- K4: atom_hiddens(bf16) = relu(concat(f_atoms, amsg) @ Wo^T + bo) ----------------
__global__ __launch_bounds__(256) void k_gemm_wo(
    const float* __restrict__ fa,
    const unsigned short* __restrict__ amsg,
    const unsigned short* __restrict__ wo,
    const float* __restrict__ bo,
    unsigned short* __restrict__ ah)
{
    __shared__ unsigned short lds[64 * KO];
    const int m0 = blockIdx.x * 64;
    const int tid = threadIdx.x;
    {
        const int r = tid >> 2, p = tid & 3;
        const int a = m0 + r;
        const bool ok = (a < A1);
        const float* src = fa + (size_t)a * AFD;
        unsigned short* drow = lds + r * KO;
#pragma unroll
        for (int i = 0; i < 13; ++i) {
            const int c0 = (i * 4 + p) * 8;
            u16x8 o;
            if (ok && c0 + 8 <= AFD) {
#pragma unroll
                for (int e = 0; e < 8; ++e) o[e] = f2b(src[c0 + e]);
            } else if (ok && c0 < AFD) {
#pragma unroll
                for (int e = 0; e < 8; ++e) o[e] = (c0 + e < AFD) ? f2b(src[c0 + e]) : (unsigned short)0;
            } else if (ok && c0 >= 160) {
                o = *(const u16x8*)(amsg + (size_t)a * HIDDEN + (c0 - 160));
            } else {
#pragma unroll
                for (int e = 0; e < 8; ++e) o[e] = 0;
            }
            *(u16x8*)(drow + c0) = o;
        }
    }
    __syncthreads();

    const int wv = tid >> 6, ln = tid & 63;
    const int l15 = ln & 15, lhi = ln >> 4;
    fx4 acc[4][4];
#pragma unroll
    for (int a = 0; a < 4; ++a)
#pragma unroll
        for (int b = 0; b < 4; ++b)
#pragma unroll
            for (int q = 0; q < 4; ++q) acc[a][b][q] = 0.f;

#pragma unroll
    for (int ks = 0; ks < 13; ++ks) {
        const int kk = ks * 32 + lhi * 8;
        bfx8 af[4], bb[4];
#pragma unroll
        for (int mf = 0; mf < 4; ++mf) {
            const int rr = mf * 16 + l15;
            af[mf] = *(const bfx8*)(lds + rr * KO + kk);
        }
#pragma unroll
        for (int nf = 0; nf < 4; ++nf) {
            const int n = wv * 64 + nf * 16 + l15;
            bb[nf] = *(const bfx8*)(wo + n * KO + kk);
        }
#pragma unroll
        for (int mf = 0; mf < 4; ++mf)
#pragma unroll
            for (int nf = 0; nf < 4; ++nf)
                acc[mf][nf] = __builtin_amdgcn_mfma_f32_16x16x32_bf16(af[mf], bb[nf], acc[mf][nf], 0, 0, 0);
    }

    __syncthreads();
    {
        const int cb = wv * 64 + l15;
        const int rb = lhi * 4;
#pragma unroll
        for (int mf = 0; mf < 4; ++mf)
#pragma unroll
            for (int j = 0; j < 4; ++j) {
                const int row = mf * 16 + rb + j;
#pragma unroll
                for (int nf = 0; nf < 4; ++nf) {
                    const int col = cb + nf * 16;
                    const int byte = (row * 512) + (((col * 2) & ~15) ^ ((row & 7) << 4)) + ((col * 2) & 15);
                    *(unsigned short*)((char*)lds + byte) = f2b(acc[mf][nf][j]);
                }
            }
    }
    __syncthreads();
#pragma unroll
    for (int i = 0; i < 8; ++i) {
        const int row = i * 8 + (tid >> 5);
        const int col16 = tid & 31;
        const int byte = row * 512 + ((col16 * 16) ^ ((row & 7) << 4));
        u16x8 c = *(const u16x8*)((const char*)lds + byte);
        const int g = m0 + row;
        if (g < A1) {
            fx4 bi0 = *(const fx4*)(bo + col16 * 8);
            fx4 bi1 = *(const fx4*)(bo + col16 * 8 + 4);
            u16x8 o;
#pragma unroll
            for (int e = 0; e < 8; ++e) {
                float v = b2f(c[e]) + (e < 4 ? bi0[e] : bi1[e - 4]);
                o[e] = f2b(v > 0.f ? v : 0.f);
            }
            *(u16x8*)(ah + (size_t)g * HIDDEN + col16 * 8) = o;
        }
    }
}

// ---------------- K5: per-molecule mean over 30 atoms ----------------
__global__ __launch_bounds__(256) void k_pool(const unsigned short* __restrict__ ah,
                                              float* __restrict__ out) {
    const int mol = blockIdx.x;
    const int h = threadIdx.x;
    const unsigned short* base = ah + ((size_t)(1 + mol * APM)) * HIDDEN + h;
    float s = 0.f;
#pragma unroll
    for (int i = 0; i < APM; ++i) s += b2f(base[(size_t)i * HIDDEN]);
    out[(size_t)mol * HIDDEN + h] = s * (1.0f / APM);
}

extern "C" void kernel_launch(void* const* d_in, const int* in_sizes, int n_in,
                              void* d_out, int out_size, void* d_ws, size_t ws_size,
                              hipStream_t stream)
{
    const float* f_atoms = (const float*)d_in[0];
    const float* f_bonds = (const float*)d_in[1];
    const int* a2b    = (const int*)d_in[2];
    const int* b2a    = (const int*)d_in[3];
    const int* b2revb = (const int*)d_in[4];
    const float* W_i  = (const float*)d_in[6];
    const float* W_h  = (const float*)d_in[7];
    const float* W_o  = (const float*)d_in[8];
    const float* b_o  = (const float*)d_in[9];
    float* out = (float*)d_out;

    char* ws = (char*)d_ws;
    size_t off = 0;
    auto alloc = [&](size_t n) { char* p = ws + off; off = (off + n + 255) & ~(size_t)255; return p; };
    unsigned short* wi   = (unsigned short*)alloc((size_t)256 * KI * 2);
    unsigned short* wh   = (unsigned short*)alloc((size_t)256 * 256 * 2);
    unsigned short* wo   = (unsigned short*)alloc((size_t)256 * KO * 2);
    unsigned short* fbb  = (unsigned short*)alloc((size_t)B1 * HIDDEN * 2 + 65536); // gload slop
    unsigned short* inp  = (unsigned short*)alloc((size_t)B1 * HIDDEN * 2 + 65536);
    unsigned short* Zbuf = (unsigned short*)alloc((size_t)B1 * HIDDEN * 2 + 65536);
    unsigned short* amsg = (unsigned short*)alloc((size_t)A1 * HIDDEN * 2);
    unsigned short* msgX = fbb;   // fbb dead after k_gemm_wi; msg lives here
    unsigned short* ah   = inp;   // inp dead after last k_eps

    k_convw<<<832, 256, 0, stream>>>(W_i, W_h, W_o, wi, wh, wo);

    const int gb64 = (B1 + 63) / 64;            // 5001
    const int ga = (A1 + 63) / 64;              // 2344
    const int gg = (A1 * 32 + 255) / 256;       // 18751
    const int ge = (B1 * 32 + 255) / 256;       // 40001

    k_convfb<<<ge, 256, 0, stream>>>(f_bonds, fbb);
    k_gemm_wi<<<gb64, 256, 0, stream>>>(fbb, wi, inp);

    // t=1: Z1 = relu(inp) @ Wh^T (relu fused in staging)
    k_gemm_z<1><<<gb64, 256, 0, stream>>>(inp, wh, Zbuf);
    k_gather<<<gg, 256, 0, stream>>>(Zbuf, a2b, amsg);
    k_eps<<<ge, 256, 0, stream>>>(inp, amsg, Zbuf, b2a, b2revb, msgX);  // msg2 (overwrites fbb)

    // t=2..5
    for (int t = 2; t <= 5; ++t) {
        k_gemm_z<0><<<gb64, 256, 0, stream>>>(msgX, wh, Zbuf);
        k_gather<<<gg, 256, 0, stream>>>(Zbuf, a2b, amsg);
        k_eps<<<ge, 256, 0, stream>>>(inp, amsg, Zbuf, b2a, b2revb, msgX);
    }

    // readout
    k_gather<<<gg, 256, 0, stream>>>(msgX, a2b, amsg);
    k_gemm_wo<<<ga, 256, 0, stream>>>(f_atoms, amsg, wo, b_o, ah);
    k_pool<<<NMOLS, 256, 0, stream>>>(ah, out);
}